// Round 13
// baseline (65.031 us; speedup 1.0000x reference)
//
#include <hip/hip_runtime.h>

// B=4, Q=512, P=512, Q_SIZE=512 (=DDIM), P_SIZE=512, V_SIZE=256 (=VDIM)
#define VDIM 256
#define DDIM 512
#define LOG2E     1.4426950408889634f
#define TWO_LOG2E 2.8853900817779268f

typedef float  f32x4   __attribute__((ext_vector_type(4)));
typedef short  short8v __attribute__((ext_vector_type(8)));

__device__ __forceinline__ unsigned short f2bf(float f) {   // RNE
    unsigned int u = __float_as_uint(f);
    u += 0x7fffu + ((u >> 16) & 1u);
    return (unsigned short)(u >> 16);
}
__device__ __forceinline__ float bf2f(unsigned short b) {
    return __uint_as_float(((unsigned int)b) << 16);
}

// trunc-split 4 floats -> 8 bf16 (hi pair-packed, lo pair-packed)
__device__ __forceinline__ void split4(const float4 f, uint2* hi, uint2* lo) {
    const unsigned u0 = __float_as_uint(f.x), u1 = __float_as_uint(f.y);
    const unsigned u2 = __float_as_uint(f.z), u3 = __float_as_uint(f.w);
    const unsigned h0 = u0 & 0xFFFF0000u, h1 = u1 & 0xFFFF0000u;
    const unsigned h2 = u2 & 0xFFFF0000u, h3 = u3 & 0xFFFF0000u;
    hi->x = (u0 >> 16) | h1;
    hi->y = (u2 >> 16) | h3;
    const float l0 = f.x - __uint_as_float(h0), l1 = f.y - __uint_as_float(h1);
    const float l2 = f.z - __uint_as_float(h2), l3 = f.w - __uint_as_float(h3);
    lo->x = (__float_as_uint(l0) >> 16) | (__float_as_uint(l1) & 0xFFFF0000u);
    lo->y = (__float_as_uint(l2) >> 16) | (__float_as_uint(l3) & 0xFFFF0000u);
}

// ---------------------------------------------------------------------------
// K0: W1->W1T (z=0), W2->W2T (z=1); 64x64 tiles, grid (4,8,2) = 64 blocks.
// ---------------------------------------------------------------------------
__global__ __launch_bounds__(256) void w_transpose(
    const float* __restrict__ W1, const float* __restrict__ W2,
    ushort* __restrict__ W1T_hi, ushort* __restrict__ W1T_lo,
    ushort* __restrict__ W2T_hi, ushort* __restrict__ W2T_lo)
{
    const float* src = blockIdx.z ? W2 : W1;
    ushort* dhi = blockIdx.z ? W2T_hi : W1T_hi;
    ushort* dlo = blockIdx.z ? W2T_lo : W1T_lo;
    const int r0 = blockIdx.y << 6, c0 = blockIdx.x << 6;   // rows 512, cols 256

    __shared__ float tile[64][65];
    const int t = threadIdx.x;
    #pragma unroll
    for (int i = 0; i < 4; ++i) {
        const int r = (i << 4) + (t >> 4);
        const int c = (t & 15) << 2;
        const float4 v = *(const float4*)(src + (size_t)(r0 + r) * 256 + c0 + c);
        tile[r][c + 0] = v.x; tile[r][c + 1] = v.y;
        tile[r][c + 2] = v.z; tile[r][c + 3] = v.w;
    }
    __syncthreads();
    #pragma unroll
    for (int i = 0; i < 4; ++i) {
        const int a  = (i << 4) + (t >> 4);
        const int bb = (t & 15) << 2;
        ushort4 hi, lo;
        float f;
        f = tile[bb + 0][a]; hi.x = f2bf(f); lo.x = f2bf(f - bf2f(hi.x));
        f = tile[bb + 1][a]; hi.y = f2bf(f); lo.y = f2bf(f - bf2f(hi.y));
        f = tile[bb + 2][a]; hi.z = f2bf(f); lo.z = f2bf(f - bf2f(hi.z));
        f = tile[bb + 3][a]; hi.w = f2bf(f); lo.w = f2bf(f - bf2f(hi.w));
        const size_t o = (size_t)(c0 + a) * 512 + r0 + bb;
        *(ushort4*)(dhi + o) = hi;
        *(ushort4*)(dlo + o) = lo;
    }
}

// ---------------------------------------------------------------------------
// K1 merged: blocks 0..255 = proj MFMA (hq@W1 -> EqT exp, hp@W2 -> Ep exp);
//            blocks 256..511 = hq[b] -> hqT bf16 hi/lo transpose (for K3).
// ---------------------------------------------------------------------------
#define SWZ(r, c) (((r) << 8) + ((c) ^ (((r) & 15) << 4)))

__global__ __launch_bounds__(256) void proj_and_transpose(
    const float* __restrict__ hq, const float* __restrict__ hp,
    const ushort* __restrict__ W1T_hi, const ushort* __restrict__ W1T_lo,
    const ushort* __restrict__ W2T_hi, const ushort* __restrict__ W2T_lo,
    ushort* __restrict__ hqT_hi, ushort* __restrict__ hqT_lo,
    float* __restrict__ EqT, float* __restrict__ Ep)
{
    __shared__ __attribute__((aligned(16))) char smem[32768];
    const int bid = blockIdx.x;
    const int t = threadIdx.x;

    if (bid >= 256) {
        // ---- hq transpose: 256 blocks, 64x64 tiles ----
        const int k  = bid - 256;
        const int z  = k >> 6;                  // batch
        const int r0 = ((k >> 3) & 7) << 6, c0 = (k & 7) << 6;
        const float* src = hq + ((size_t)z << 18);
        ushort* dhi = hqT_hi + ((size_t)z << 18);
        ushort* dlo = hqT_lo + ((size_t)z << 18);
        float (*tile)[65] = (float(*)[65])smem;
        #pragma unroll
        for (int i = 0; i < 4; ++i) {
            const int r = (i << 4) + (t >> 4);
            const int c = (t & 15) << 2;
            const float4 v = *(const float4*)(src + (size_t)(r0 + r) * 512 + c0 + c);
            tile[r][c + 0] = v.x; tile[r][c + 1] = v.y;
            tile[r][c + 2] = v.z; tile[r][c + 3] = v.w;
        }
        __syncthreads();
        #pragma unroll
        for (int i = 0; i < 4; ++i) {
            const int a  = (i << 4) + (t >> 4);
            const int bb = (t & 15) << 2;
            ushort4 hi, lo;
            float f;
            f = tile[bb + 0][a]; hi.x = f2bf(f); lo.x = f2bf(f - bf2f(hi.x));
            f = tile[bb + 1][a]; hi.y = f2bf(f); lo.y = f2bf(f - bf2f(hi.y));
            f = tile[bb + 2][a]; hi.z = f2bf(f); lo.z = f2bf(f - bf2f(hi.z));
            f = tile[bb + 3][a]; hi.w = f2bf(f); lo.w = f2bf(f - bf2f(hi.w));
            const size_t o = (size_t)(c0 + a) * 512 + r0 + bb;
            *(ushort4*)(dhi + o) = hi;
            *(ushort4*)(dlo + o) = lo;
        }
        return;
    }

    // ---- proj MFMA: bid 0..255 -> by = bid>>2 (0..63), n0 = (bid&3)<<6 ----
    const int by = bid >> 2;
    const bool isQ = by < 32;
    const int m0 = (by & 31) << 6;
    const int n0 = (bid & 3) << 6;
    const float*  __restrict__ A   = isQ ? hq : hp;
    const ushort* __restrict__ Bhi = isQ ? W1T_hi : W2T_hi;
    const ushort* __restrict__ Blo = isQ ? W1T_lo : W2T_lo;

    char* AsB = smem;
    char* BsB = smem + 16384;

    const int w = t >> 6, l = t & 63;
    const int moff = (w & 1) << 5, noff = (w >> 1) << 5;

    f32x4 acc[2][2];
    #pragma unroll
    for (int i = 0; i < 2; ++i)
        #pragma unroll
        for (int j = 0; j < 2; ++j)
            acc[i][j] = (f32x4){0.f, 0.f, 0.f, 0.f};

    const int sr = t >> 2;
    const int sc = t & 3;
    const size_t argA = (size_t)(m0 + sr) * 512;
    const size_t argB = (size_t)(n0 + sr) * 512;

    for (int k0 = 0; k0 < 512; k0 += 64) {
        const float4 f0 = *(const float4*)(A + argA + k0 + (sc << 4) + 0);
        const float4 f1 = *(const float4*)(A + argA + k0 + (sc << 4) + 4);
        const float4 f2 = *(const float4*)(A + argA + k0 + (sc << 4) + 8);
        const float4 f3 = *(const float4*)(A + argA + k0 + (sc << 4) + 12);
        const uint4 b0 = *(const uint4*)(Bhi + argB + k0 + (sc << 4));
        const uint4 b1 = *(const uint4*)(Bhi + argB + k0 + (sc << 4) + 8);
        const uint4 b2 = *(const uint4*)(Blo + argB + k0 + (sc << 4));
        const uint4 b3 = *(const uint4*)(Blo + argB + k0 + (sc << 4) + 8);

        uint4 ah0, al0, ah1, al1;
        split4(f0, (uint2*)&ah0.x, (uint2*)&al0.x);
        split4(f1, (uint2*)&ah0.z, (uint2*)&al0.z);
        split4(f2, (uint2*)&ah1.x, (uint2*)&al1.x);
        split4(f3, (uint2*)&ah1.z, (uint2*)&al1.z);

        __syncthreads();
        *(uint4*)(AsB + SWZ(sr, (sc << 5)))            = ah0;
        *(uint4*)(AsB + SWZ(sr, (sc << 5) + 16))       = ah1;
        *(uint4*)(AsB + SWZ(sr, 128 + (sc << 5)))      = al0;
        *(uint4*)(AsB + SWZ(sr, 128 + (sc << 5) + 16)) = al1;
        *(uint4*)(BsB + SWZ(sr, (sc << 5)))            = b0;
        *(uint4*)(BsB + SWZ(sr, (sc << 5) + 16))       = b1;
        *(uint4*)(BsB + SWZ(sr, 128 + (sc << 5)))      = b2;
        *(uint4*)(BsB + SWZ(sr, 128 + (sc << 5) + 16)) = b3;
        __syncthreads();

        #pragma unroll
        for (int kc = 0; kc < 2; ++kc) {
            const int colh = (kc << 6) + ((l >> 4) << 4);
            short8v ahi[2], alo[2], bhi[2], blo[2];
            #pragma unroll
            for (int mt = 0; mt < 2; ++mt) {
                const int r = moff + (mt << 4) + (l & 15);
                ahi[mt] = *(const short8v*)(AsB + SWZ(r, colh));
                alo[mt] = *(const short8v*)(AsB + SWZ(r, colh + 128));
            }
            #pragma unroll
            for (int nt = 0; nt < 2; ++nt) {
                const int r = noff + (nt << 4) + (l & 15);
                bhi[nt] = *(const short8v*)(BsB + SWZ(r, colh));
                blo[nt] = *(const short8v*)(BsB + SWZ(r, colh + 128));
            }
            #pragma unroll
            for (int mt = 0; mt < 2; ++mt)
                #pragma unroll
                for (int nt = 0; nt < 2; ++nt) {
                    acc[mt][nt] = __builtin_amdgcn_mfma_f32_16x16x32_bf16(ahi[mt], bhi[nt], acc[mt][nt], 0, 0, 0);
                    acc[mt][nt] = __builtin_amdgcn_mfma_f32_16x16x32_bf16(ahi[mt], blo[nt], acc[mt][nt], 0, 0, 0);
                    acc[mt][nt] = __builtin_amdgcn_mfma_f32_16x16x32_bf16(alo[mt], bhi[nt], acc[mt][nt], 0, 0, 0);
                }
        }
    }

    #pragma unroll
    for (int mt = 0; mt < 2; ++mt)
        #pragma unroll
        for (int nt = 0; nt < 2; ++nt)
            #pragma unroll
            for (int r = 0; r < 4; ++r) {
                const int row = m0 + moff + (mt << 4) + ((l >> 4) << 2) + r;
                const int col = n0 + noff + (nt << 4) + (l & 15);
                const float e = __builtin_amdgcn_exp2f(acc[mt][nt][r] * TWO_LOG2E);
                if (isQ) {
                    const int bb = row >> 9, q = row & 511;
                    EqT[((((size_t)bb << 6) + (col >> 2)) * 512 + q) * 4 + (col & 3)] = e;
                } else {
                    Ep[(size_t)row * VDIM + col] = e;
                }
            }
}

// ---------------------------------------------------------------------------
// K2: block = (b, 4 p-rows), 512 threads, thread t owns q=t. grid = 512.
// DEPTH-2 prefetch ring on the Eq stream: compute(vi) covers ~224 cyc,
// L2 hit latency ~200 cyc -> loads fully hidden (round-13 change).
// 4-way rcp batching, bf16 hi/lo a-write.
// ---------------------------------------------------------------------------
template<bool FUSED>
__global__ __launch_bounds__(512) void score_softmax(
    const float4* __restrict__ EqT, const float* __restrict__ Ep,
    const float* __restrict__ vvec, const float* __restrict__ hq,
    ushort* __restrict__ a_hi, ushort* __restrict__ a_lo,
    float* __restrict__ out)
{
    const int blk = blockIdx.x;           // 0..511
    const int b   = blk >> 7;
    const int p0  = (blk & 127) << 2;

    __shared__ __attribute__((aligned(16))) float score[4][512];
    const int t = threadIdx.x;            // q = t

    const float4* __restrict__ wv  = (const float4*)vvec;
    const float4* __restrict__ eqp = EqT + ((size_t)b << 15) + t;
    const float*  epb              = Ep + (size_t)((b << 9) + p0) * VDIM;

    float a0 = 0.f, a1 = 0.f, a2 = 0.f, a3 = 0.f;
    float4 e0 = eqp[0];
    float4 e1 = eqp[1 << 9];

    #pragma unroll 8
    for (int vi = 0; vi < 64; ++vi) {
        const float4 ec = e0;
        e0 = e1;
        if (vi < 62) e1 = eqp[(size_t)(vi + 2) << 9];   // depth-2 prefetch
        const float4 w = wv[vi];                        // uniform
#define ROWTERM(i, accv) { \
        const float4 p = *((const float4*)(epb + (i) * VDIM) + vi); \
        const float t0 = fmaf(p.x, ec.x, 1.f), t1 = fmaf(p.y, ec.y, 1.f); \
        const float t2 = fmaf(p.z, ec.z, 1.f), t3 = fmaf(p.w, ec.w, 1.f); \
        const float d01 = t0 * t1, d23 = t2 * t3, den = d01 * d23; \
        const float n01 = fmaf(w.x, t1, w.y * t0); \
        const float n23 = fmaf(w.z, t3, w.w * t2); \
        const float num = fmaf(n01, d23, n23 * d01); \
        accv = fmaf(num, __builtin_amdgcn_rcpf(den), accv); }
        ROWTERM(0, a0) ROWTERM(1, a1) ROWTERM(2, a2) ROWTERM(3, a3)
#undef ROWTERM
    }
    score[0][t] = a0; score[1][t] = a1; score[2][t] = a2; score[3][t] = a3;
    __syncthreads();

    // softmax over q (true score = const - 2*acc); waves 0-3, one per p-row
    {
        const int wid = t >> 6, lane = t & 63;
        if (wid < 4) {
            float vals[8];
            float m = -1e30f;
            #pragma unroll
            for (int i = 0; i < 8; ++i) {
                vals[i] = -2.f * score[wid][lane + (i << 6)];
                m = fmaxf(m, vals[i]);
            }
            #pragma unroll
            for (int off = 32; off; off >>= 1) m = fmaxf(m, __shfl_xor(m, off));
            float sum = 0.f;
            #pragma unroll
            for (int i = 0; i < 8; ++i) {
                vals[i] = __builtin_amdgcn_exp2f((vals[i] - m) * LOG2E);
                sum += vals[i];
            }
            #pragma unroll
            for (int off = 32; off; off >>= 1) sum += __shfl_xor(sum, off);
            const float inv = __builtin_amdgcn_rcpf(sum);
            #pragma unroll
            for (int i = 0; i < 8; ++i) score[wid][lane + (i << 6)] = vals[i] * inv;
        }
    }
    __syncthreads();

    if (!FUSED) {
        #pragma unroll
        for (int r = 0; r < 4; ++r) {
            const float f = score[r][t];
            const ushort h  = f2bf(f);
            const ushort lo = f2bf(f - bf2f(h));
            a_hi[(size_t)((b << 9) + p0 + r) * 512 + t] = h;
            a_lo[(size_t)((b << 9) + p0 + r) * 512 + t] = lo;
        }
    } else {
        float ax[4] = {};
        #pragma unroll 4
        for (int q = 0; q < 512; ++q) {
            const float h = hq[(size_t)((b << 9) + q) * DDIM + t];
            #pragma unroll
            for (int r = 0; r < 4; ++r) ax[r] = fmaf(score[r][q], h, ax[r]);
        }
        #pragma unroll
        for (int r = 0; r < 4; ++r)
            out[(size_t)((b << 9) + p0 + r) * DDIM + t] = ax[r];
    }
}

// ---------------------------------------------------------------------------
// K3: out = a @ hq (batched). 32x64 tile, grid (8,64) = 512 blocks (2/CU).
// A = a hi/lo bf16 row-major, B = hqT hi/lo.
// ---------------------------------------------------------------------------
__global__ __launch_bounds__(256) void out_mfma(
    const ushort* __restrict__ Ahi, const ushort* __restrict__ Alo,
    const ushort* __restrict__ Bhi_, const ushort* __restrict__ Blo_,
    float* __restrict__ C)
{
    const int m0 = blockIdx.y << 5;       // 32-row tiles, 64 of them
    const int n0 = blockIdx.x << 6;
    const size_t off = (size_t)(m0 >> 9) << 18;
    const ushort* __restrict__ Bhi = Bhi_ + off;
    const ushort* __restrict__ Blo = Blo_ + off;

    __shared__ __attribute__((aligned(16))) ushort As[32 * 128];   // 8KB
    __shared__ __attribute__((aligned(16))) ushort Bs[64 * 128];   // 16KB
    char* AsB = (char*)As;
    char* BsB = (char*)Bs;

    const int t = threadIdx.x;
    const int w = t >> 6, l = t & 63;
    const int moff = (w & 1) << 4, noff = (w >> 1) << 5;

    f32x4 acc[2];
    acc[0] = (f32x4){0.f, 0.f, 0.f, 0.f};
    acc[1] = (f32x4){0.f, 0.f, 0.f, 0.f};

    const int sra = t >> 3, sca = t & 7;          // A: 32 rows x 8 chunks
    const int srb = t >> 2, scb = t & 3;          // B: 64 rows x 4 chunk-pairs
    const size_t argA = (size_t)(m0 + sra) * 512;
    const size_t argB = (size_t)(n0 + srb) * 512;

    for (int k0 = 0; k0 < 512; k0 += 64) {
        const uint4 a0 = *(const uint4*)(Ahi + argA + k0 + (sca << 3));
        const uint4 a1 = *(const uint4*)(Alo + argA + k0 + (sca << 3));
        const uint4 b0 = *(const uint4*)(Bhi + argB + k0 + (scb << 4));
        const uint4 b1 = *(const uint4*)(Bhi + argB + k0 + (scb << 4) + 8);
        const uint4 b2 = *(const uint4*)(Blo + argB + k0 + (scb << 4));
        const uint4 b3 = *(const uint4*)(Blo + argB + k0 + (scb << 4) + 8);
        __syncthreads();
        *(uint4*)(AsB + SWZ(sra, (sca << 4)))          = a0;
        *(uint4*)(AsB + SWZ(sra, 128 + (sca << 4)))    = a1;
        *(uint4*)(BsB + SWZ(srb, (scb << 5)))          = b0;
        *(uint4*)(BsB + SWZ(srb, (scb << 5) + 16))     = b1;
        *(uint4*)(BsB + SWZ(srb, 128 + (scb << 5)))    = b2;
        *(uint4*)(BsB + SWZ(srb, 128 + (scb << 5) + 16)) = b3;
        __syncthreads();
        #pragma unroll
        for (int kc = 0; kc < 2; ++kc) {
            const int colh = (kc << 6) + ((l >> 4) << 4);
            const int ra = moff + (l & 15);
            const short8v ahi = *(const short8v*)(AsB + SWZ(ra, colh));
            const short8v alo = *(const short8v*)(AsB + SWZ(ra, colh + 128));
            #pragma unroll
            for (int nt = 0; nt < 2; ++nt) {
                const int rb = noff + (nt << 4) + (l & 15);
                const short8v bhi = *(const short8v*)(BsB + SWZ(rb, colh));
                const short8v blo = *(const short8v*)(BsB + SWZ(rb, colh + 128));
                acc[nt] = __builtin_amdgcn_mfma_f32_16x16x32_bf16(ahi, bhi, acc[nt], 0, 0, 0);
                acc[nt] = __builtin_amdgcn_mfma_f32_16x16x32_bf16(ahi, blo, acc[nt], 0, 0, 0);
                acc[nt] = __builtin_amdgcn_mfma_f32_16x16x32_bf16(alo, bhi, acc[nt], 0, 0, 0);
            }
        }
    }

    #pragma unroll
    for (int nt = 0; nt < 2; ++nt)
        #pragma unroll
        for (int r = 0; r < 4; ++r) {
            const int row = m0 + moff + ((l >> 4) << 2) + r;
            const int col = n0 + noff + (nt << 4) + (l & 15);
            C[(size_t)row * 512 + col] = acc[nt][r];
        }
}

// ---------------------------------------------------------------------------
// Fallback f32 projection for tiny workspaces.
// ---------------------------------------------------------------------------
__global__ __launch_bounds__(256) void proj_exp_gemm_f32(
    const float* __restrict__ hq, const float* __restrict__ hp,
    const float* __restrict__ W1, const float* __restrict__ W2,
    float* __restrict__ Eq, float* __restrict__ Ep)
{
    const int by = blockIdx.y;
    const float *A, *W;
    if (by < 64) { A = hq; W = W1; }
    else         { A = hp; W = W2; }
    const int m0 = (by & 63) * 32;
    const int n0 = blockIdx.x * 64;

    __shared__ __attribute__((aligned(16))) float As[16][36];
    __shared__ __attribute__((aligned(16))) float Bs[16][68];

    const int tid  = threadIdx.x;
    const int tr = tid >> 4, tc = tid & 15;
    const int la_r = tid >> 3, la_c = (tid & 7) << 1;
    const int lb_r = tid >> 4, lb_c = (tid & 15) << 2;

    float acc[2][4] = {};
    for (int k0 = 0; k0 < 512; k0 += 16) {
        float2 a2 = *(const float2*)(A + (size_t)(m0 + la_r) * 512 + k0 + la_c);
        float4 b4 = *(const float4*)(W + (size_t)(k0 + lb_r) * VDIM + n0 + lb_c);
        __syncthreads();
        As[la_c + 0][la_r] = a2.x;
        As[la_c + 1][la_r] = a2.y;
        *(float4*)&Bs[lb_r][lb_c] = b4;
        __syncthreads();
        #pragma unroll
        for (int kk = 0; kk < 16; ++kk) {
            float2 av = *(const float2*)&As[kk][tr << 1];
            float4 bv = *(const float4*)&Bs[kk][tc << 2];
            const float* ap = (const float*)&av;
            const float* bp = (const float*)&bv;
            #pragma unroll
            for (int i = 0; i < 2; ++i)
                #pragma unroll
                for (int j = 0; j < 4; ++j)
                    acc[i][j] = fmaf(ap[i], bp[j], acc[i][j]);
        }
    }
    if (by < 64) {
        float4* EqT = (float4*)Eq;
        const int bb = m0 >> 9, qb = m0 & 511;
        const int vi = (blockIdx.x << 4) + tc;
        #pragma unroll
        for (int i = 0; i < 2; ++i) {
            float4 r;
            r.x = __builtin_amdgcn_exp2f(acc[i][0] * TWO_LOG2E);
            r.y = __builtin_amdgcn_exp2f(acc[i][1] * TWO_LOG2E);
            r.z = __builtin_amdgcn_exp2f(acc[i][2] * TWO_LOG2E);
            r.w = __builtin_amdgcn_exp2f(acc[i][3] * TWO_LOG2E);
            EqT[((size_t)(bb << 6) + vi) * 512 + qb + (tr << 1) + i] = r;
        }
    } else {
        #pragma unroll
        for (int i = 0; i < 2; ++i) {
            float4 r;
            r.x = __builtin_amdgcn_exp2f(acc[i][0] * TWO_LOG2E);
            r.y = __builtin_amdgcn_exp2f(acc[i][1] * TWO_LOG2E);
            r.z = __builtin_amdgcn_exp2f(acc[i][2] * TWO_LOG2E);
            r.w = __builtin_amdgcn_exp2f(acc[i][3] * TWO_LOG2E);
            *(float4*)(Ep + (size_t)(m0 + (tr << 1) + i) * VDIM + n0 + (tc << 2)) = r;
        }
    }
}

// ---------------------------------------------------------------------------
extern "C" void kernel_launch(void* const* d_in, const int* in_sizes, int n_in,
                              void* d_out, int out_size, void* d_ws, size_t ws_size,
                              hipStream_t stream)
{
    const float* hq = (const float*)d_in[0];   // [4,512,512]
    const float* hp = (const float*)d_in[1];   // [4,512,512]
    const float* W1 = (const float*)d_in[2];   // [512,256]
    const float* W2 = (const float*)d_in[3];   // [512,256]
    const float* vv = (const float*)d_in[4];   // [256]
    float* out = (float*)d_out;                // [4,512,512]

    float* EqT = (float*)d_ws;                 // [4][64][512] float4 = 2MB
    float* Ep  = EqT + 524288;                 // [2048,256] f32 = 2MB
    ushort* u  = (ushort*)(Ep + 524288);
    ushort* hqT_hi = u; u += 1048576;
    ushort* hqT_lo = u; u += 1048576;
    ushort* W1T_hi = u; u += 131072;
    ushort* W1T_lo = u; u += 131072;
    ushort* W2T_hi = u; u += 131072;
    ushort* W2T_lo = u; u += 131072;
    ushort* a_hi   = u; u += 1048576;
    ushort* a_lo   = u; u += 1048576;
    const size_t need = (size_t)((char*)u - (char*)d_ws);

    if (ws_size >= need) {
        w_transpose<<<dim3(4, 8, 2), 256, 0, stream>>>(
            W1, W2, W1T_hi, W1T_lo, W2T_hi, W2T_lo);
        proj_and_transpose<<<512, 256, 0, stream>>>(
            hq, hp, W1T_hi, W1T_lo, W2T_hi, W2T_lo, hqT_hi, hqT_lo, EqT, Ep);
        score_softmax<false><<<512, 512, 0, stream>>>(
            (const float4*)EqT, Ep, vv, hq, a_hi, a_lo, out);
        out_mfma<<<dim3(8, 64), 256, 0, stream>>>(a_hi, a_lo, hqT_hi, hqT_lo, out);
    } else {
        proj_exp_gemm_f32<<<dim3(4, 128), 256, 0, stream>>>(hq, hp, W1, W2, EqT, Ep);
        score_softmax<true><<<512, 512, 0, stream>>>(
            (const float4*)EqT, Ep, vv, hq, nullptr, nullptr, out);
    }
}

// Round 14
// 56.709 us; speedup vs baseline: 1.1467x; 1.1467x over previous
//
#include <hip/hip_runtime.h>

// B=4, Q=512, P=512, Q_SIZE=512 (=DDIM), P_SIZE=512, V_SIZE=256 (=VDIM)
#define VDIM 256
#define DDIM 512
#define LOG2E     1.4426950408889634f
#define TWO_LOG2E 2.8853900817779268f

typedef float  f32x4   __attribute__((ext_vector_type(4)));
typedef short  short8v __attribute__((ext_vector_type(8)));

__device__ __forceinline__ unsigned short f2bf(float f) {   // RNE
    unsigned int u = __float_as_uint(f);
    u += 0x7fffu + ((u >> 16) & 1u);
    return (unsigned short)(u >> 16);
}
__device__ __forceinline__ float bf2f(unsigned short b) {
    return __uint_as_float(((unsigned int)b) << 16);
}

// trunc-split 4 floats -> 8 bf16 (hi pair-packed, lo pair-packed)
__device__ __forceinline__ void split4(const float4 f, uint2* hi, uint2* lo) {
    const unsigned u0 = __float_as_uint(f.x), u1 = __float_as_uint(f.y);
    const unsigned u2 = __float_as_uint(f.z), u3 = __float_as_uint(f.w);
    const unsigned h0 = u0 & 0xFFFF0000u, h1 = u1 & 0xFFFF0000u;
    const unsigned h2 = u2 & 0xFFFF0000u, h3 = u3 & 0xFFFF0000u;
    hi->x = (u0 >> 16) | h1;
    hi->y = (u2 >> 16) | h3;
    const float l0 = f.x - __uint_as_float(h0), l1 = f.y - __uint_as_float(h1);
    const float l2 = f.z - __uint_as_float(h2), l3 = f.w - __uint_as_float(h3);
    lo->x = (__float_as_uint(l0) >> 16) | (__float_as_uint(l1) & 0xFFFF0000u);
    lo->y = (__float_as_uint(l2) >> 16) | (__float_as_uint(l3) & 0xFFFF0000u);
}

// ---------------------------------------------------------------------------
// K0: W1->W1T (z=0), W2->W2T (z=1); 64x64 tiles, grid (4,8,2) = 64 blocks.
// ---------------------------------------------------------------------------
__global__ __launch_bounds__(256) void w_transpose(
    const float* __restrict__ W1, const float* __restrict__ W2,
    ushort* __restrict__ W1T_hi, ushort* __restrict__ W1T_lo,
    ushort* __restrict__ W2T_hi, ushort* __restrict__ W2T_lo)
{
    const float* src = blockIdx.z ? W2 : W1;
    ushort* dhi = blockIdx.z ? W2T_hi : W1T_hi;
    ushort* dlo = blockIdx.z ? W2T_lo : W1T_lo;
    const int r0 = blockIdx.y << 6, c0 = blockIdx.x << 6;   // rows 512, cols 256

    __shared__ float tile[64][65];
    const int t = threadIdx.x;
    #pragma unroll
    for (int i = 0; i < 4; ++i) {
        const int r = (i << 4) + (t >> 4);
        const int c = (t & 15) << 2;
        const float4 v = *(const float4*)(src + (size_t)(r0 + r) * 256 + c0 + c);
        tile[r][c + 0] = v.x; tile[r][c + 1] = v.y;
        tile[r][c + 2] = v.z; tile[r][c + 3] = v.w;
    }
    __syncthreads();
    #pragma unroll
    for (int i = 0; i < 4; ++i) {
        const int a  = (i << 4) + (t >> 4);
        const int bb = (t & 15) << 2;
        ushort4 hi, lo;
        float f;
        f = tile[bb + 0][a]; hi.x = f2bf(f); lo.x = f2bf(f - bf2f(hi.x));
        f = tile[bb + 1][a]; hi.y = f2bf(f); lo.y = f2bf(f - bf2f(hi.y));
        f = tile[bb + 2][a]; hi.z = f2bf(f); lo.z = f2bf(f - bf2f(hi.z));
        f = tile[bb + 3][a]; hi.w = f2bf(f); lo.w = f2bf(f - bf2f(hi.w));
        const size_t o = (size_t)(c0 + a) * 512 + r0 + bb;
        *(ushort4*)(dhi + o) = hi;
        *(ushort4*)(dlo + o) = lo;
    }
}

// ---------------------------------------------------------------------------
// K1 merged: blocks 0..255 = proj MFMA (hq@W1 -> EqT exp, hp@W2 -> Ep exp);
//            blocks 256..511 = hq[b] -> hqT bf16 hi/lo transpose (for K3).
// ---------------------------------------------------------------------------
#define SWZ(r, c) (((r) << 8) + ((c) ^ (((r) & 15) << 4)))

__global__ __launch_bounds__(256) void proj_and_transpose(
    const float* __restrict__ hq, const float* __restrict__ hp,
    const ushort* __restrict__ W1T_hi, const ushort* __restrict__ W1T_lo,
    const ushort* __restrict__ W2T_hi, const ushort* __restrict__ W2T_lo,
    ushort* __restrict__ hqT_hi, ushort* __restrict__ hqT_lo,
    float* __restrict__ EqT, float* __restrict__ Ep)
{
    __shared__ __attribute__((aligned(16))) char smem[32768];
    const int bid = blockIdx.x;
    const int t = threadIdx.x;

    if (bid >= 256) {
        // ---- hq transpose: 256 blocks, 64x64 tiles ----
        const int k  = bid - 256;
        const int z  = k >> 6;                  // batch
        const int r0 = ((k >> 3) & 7) << 6, c0 = (k & 7) << 6;
        const float* src = hq + ((size_t)z << 18);
        ushort* dhi = hqT_hi + ((size_t)z << 18);
        ushort* dlo = hqT_lo + ((size_t)z << 18);
        float (*tile)[65] = (float(*)[65])smem;
        #pragma unroll
        for (int i = 0; i < 4; ++i) {
            const int r = (i << 4) + (t >> 4);
            const int c = (t & 15) << 2;
            const float4 v = *(const float4*)(src + (size_t)(r0 + r) * 512 + c0 + c);
            tile[r][c + 0] = v.x; tile[r][c + 1] = v.y;
            tile[r][c + 2] = v.z; tile[r][c + 3] = v.w;
        }
        __syncthreads();
        #pragma unroll
        for (int i = 0; i < 4; ++i) {
            const int a  = (i << 4) + (t >> 4);
            const int bb = (t & 15) << 2;
            ushort4 hi, lo;
            float f;
            f = tile[bb + 0][a]; hi.x = f2bf(f); lo.x = f2bf(f - bf2f(hi.x));
            f = tile[bb + 1][a]; hi.y = f2bf(f); lo.y = f2bf(f - bf2f(hi.y));
            f = tile[bb + 2][a]; hi.z = f2bf(f); lo.z = f2bf(f - bf2f(hi.z));
            f = tile[bb + 3][a]; hi.w = f2bf(f); lo.w = f2bf(f - bf2f(hi.w));
            const size_t o = (size_t)(c0 + a) * 512 + r0 + bb;
            *(ushort4*)(dhi + o) = hi;
            *(ushort4*)(dlo + o) = lo;
        }
        return;
    }

    // ---- proj MFMA: bid 0..255 -> by = bid>>2 (0..63), n0 = (bid&3)<<6 ----
    const int by = bid >> 2;
    const bool isQ = by < 32;
    const int m0 = (by & 31) << 6;
    const int n0 = (bid & 3) << 6;
    const float*  __restrict__ A   = isQ ? hq : hp;
    const ushort* __restrict__ Bhi = isQ ? W1T_hi : W2T_hi;
    const ushort* __restrict__ Blo = isQ ? W1T_lo : W2T_lo;

    char* AsB = smem;
    char* BsB = smem + 16384;

    const int w = t >> 6, l = t & 63;
    const int moff = (w & 1) << 5, noff = (w >> 1) << 5;

    f32x4 acc[2][2];
    #pragma unroll
    for (int i = 0; i < 2; ++i)
        #pragma unroll
        for (int j = 0; j < 2; ++j)
            acc[i][j] = (f32x4){0.f, 0.f, 0.f, 0.f};

    const int sr = t >> 2;
    const int sc = t & 3;
    const size_t argA = (size_t)(m0 + sr) * 512;
    const size_t argB = (size_t)(n0 + sr) * 512;

    for (int k0 = 0; k0 < 512; k0 += 64) {
        const float4 f0 = *(const float4*)(A + argA + k0 + (sc << 4) + 0);
        const float4 f1 = *(const float4*)(A + argA + k0 + (sc << 4) + 4);
        const float4 f2 = *(const float4*)(A + argA + k0 + (sc << 4) + 8);
        const float4 f3 = *(const float4*)(A + argA + k0 + (sc << 4) + 12);
        const uint4 b0 = *(const uint4*)(Bhi + argB + k0 + (sc << 4));
        const uint4 b1 = *(const uint4*)(Bhi + argB + k0 + (sc << 4) + 8);
        const uint4 b2 = *(const uint4*)(Blo + argB + k0 + (sc << 4));
        const uint4 b3 = *(const uint4*)(Blo + argB + k0 + (sc << 4) + 8);

        uint4 ah0, al0, ah1, al1;
        split4(f0, (uint2*)&ah0.x, (uint2*)&al0.x);
        split4(f1, (uint2*)&ah0.z, (uint2*)&al0.z);
        split4(f2, (uint2*)&ah1.x, (uint2*)&al1.x);
        split4(f3, (uint2*)&ah1.z, (uint2*)&al1.z);

        __syncthreads();
        *(uint4*)(AsB + SWZ(sr, (sc << 5)))            = ah0;
        *(uint4*)(AsB + SWZ(sr, (sc << 5) + 16))       = ah1;
        *(uint4*)(AsB + SWZ(sr, 128 + (sc << 5)))      = al0;
        *(uint4*)(AsB + SWZ(sr, 128 + (sc << 5) + 16)) = al1;
        *(uint4*)(BsB + SWZ(sr, (sc << 5)))            = b0;
        *(uint4*)(BsB + SWZ(sr, (sc << 5) + 16))       = b1;
        *(uint4*)(BsB + SWZ(sr, 128 + (sc << 5)))      = b2;
        *(uint4*)(BsB + SWZ(sr, 128 + (sc << 5) + 16)) = b3;
        __syncthreads();

        #pragma unroll
        for (int kc = 0; kc < 2; ++kc) {
            const int colh = (kc << 6) + ((l >> 4) << 4);
            short8v ahi[2], alo[2], bhi[2], blo[2];
            #pragma unroll
            for (int mt = 0; mt < 2; ++mt) {
                const int r = moff + (mt << 4) + (l & 15);
                ahi[mt] = *(const short8v*)(AsB + SWZ(r, colh));
                alo[mt] = *(const short8v*)(AsB + SWZ(r, colh + 128));
            }
            #pragma unroll
            for (int nt = 0; nt < 2; ++nt) {
                const int r = noff + (nt << 4) + (l & 15);
                bhi[nt] = *(const short8v*)(BsB + SWZ(r, colh));
                blo[nt] = *(const short8v*)(BsB + SWZ(r, colh + 128));
            }
            #pragma unroll
            for (int mt = 0; mt < 2; ++mt)
                #pragma unroll
                for (int nt = 0; nt < 2; ++nt) {
                    acc[mt][nt] = __builtin_amdgcn_mfma_f32_16x16x32_bf16(ahi[mt], bhi[nt], acc[mt][nt], 0, 0, 0);
                    acc[mt][nt] = __builtin_amdgcn_mfma_f32_16x16x32_bf16(ahi[mt], blo[nt], acc[mt][nt], 0, 0, 0);
                    acc[mt][nt] = __builtin_amdgcn_mfma_f32_16x16x32_bf16(alo[mt], bhi[nt], acc[mt][nt], 0, 0, 0);
                }
        }
    }

    #pragma unroll
    for (int mt = 0; mt < 2; ++mt)
        #pragma unroll
        for (int nt = 0; nt < 2; ++nt)
            #pragma unroll
            for (int r = 0; r < 4; ++r) {
                const int row = m0 + moff + (mt << 4) + ((l >> 4) << 2) + r;
                const int col = n0 + noff + (nt << 4) + (l & 15);
                const float e = __builtin_amdgcn_exp2f(acc[mt][nt][r] * TWO_LOG2E);
                if (isQ) {
                    const int bb = row >> 9, q = row & 511;
                    EqT[((((size_t)bb << 6) + (col >> 2)) * 512 + q) * 4 + (col & 3)] = e;
                } else {
                    Ep[(size_t)row * VDIM + col] = e;
                }
            }
}

// ---------------------------------------------------------------------------
// K2: block = (b, 4 p-rows), 512 threads, thread t owns q=t. grid = 512.
// (round-8/10/12 proven config: ~50-60 VGPR, no spill). Depth-1 e-prefetch,
// 4-way rcp batching, bf16 hi/lo a-write.
// ---------------------------------------------------------------------------
template<bool FUSED>
__global__ __launch_bounds__(512) void score_softmax(
    const float4* __restrict__ EqT, const float* __restrict__ Ep,
    const float* __restrict__ vvec, const float* __restrict__ hq,
    ushort* __restrict__ a_hi, ushort* __restrict__ a_lo,
    float* __restrict__ out)
{
    const int blk = blockIdx.x;           // 0..511
    const int b   = blk >> 7;
    const int p0  = (blk & 127) << 2;

    __shared__ __attribute__((aligned(16))) float score[4][512];
    const int t = threadIdx.x;            // q = t

    const float4* __restrict__ wv  = (const float4*)vvec;
    const float4* __restrict__ eqp = EqT + ((size_t)b << 15) + t;
    const float*  epb              = Ep + (size_t)((b << 9) + p0) * VDIM;

    float a0 = 0.f, a1 = 0.f, a2 = 0.f, a3 = 0.f;
    float4 e = eqp[0];

    #pragma unroll 4
    for (int vi = 0; vi < 64; ++vi) {
        const float4 ec = e;
        if (vi < 63) e = eqp[(vi + 1) << 9];    // prefetch next
        const float4 w = wv[vi];                // uniform
#define ROWTERM(i, accv) { \
        const float4 p = *((const float4*)(epb + (i) * VDIM) + vi); \
        const float t0 = fmaf(p.x, ec.x, 1.f), t1 = fmaf(p.y, ec.y, 1.f); \
        const float t2 = fmaf(p.z, ec.z, 1.f), t3 = fmaf(p.w, ec.w, 1.f); \
        const float d01 = t0 * t1, d23 = t2 * t3, den = d01 * d23; \
        const float n01 = fmaf(w.x, t1, w.y * t0); \
        const float n23 = fmaf(w.z, t3, w.w * t2); \
        const float num = fmaf(n01, d23, n23 * d01); \
        accv = fmaf(num, __builtin_amdgcn_rcpf(den), accv); }
        ROWTERM(0, a0) ROWTERM(1, a1) ROWTERM(2, a2) ROWTERM(3, a3)
#undef ROWTERM
    }
    score[0][t] = a0; score[1][t] = a1; score[2][t] = a2; score[3][t] = a3;
    __syncthreads();

    // softmax over q (true score = const - 2*acc); waves 0-3, one per p-row
    {
        const int wid = t >> 6, lane = t & 63;
        if (wid < 4) {
            float vals[8];
            float m = -1e30f;
            #pragma unroll
            for (int i = 0; i < 8; ++i) {
                vals[i] = -2.f * score[wid][lane + (i << 6)];
                m = fmaxf(m, vals[i]);
            }
            #pragma unroll
            for (int off = 32; off; off >>= 1) m = fmaxf(m, __shfl_xor(m, off));
            float sum = 0.f;
            #pragma unroll
            for (int i = 0; i < 8; ++i) {
                vals[i] = __builtin_amdgcn_exp2f((vals[i] - m) * LOG2E);
                sum += vals[i];
            }
            #pragma unroll
            for (int off = 32; off; off >>= 1) sum += __shfl_xor(sum, off);
            const float inv = __builtin_amdgcn_rcpf(sum);
            #pragma unroll
            for (int i = 0; i < 8; ++i) score[wid][lane + (i << 6)] = vals[i] * inv;
        }
    }
    __syncthreads();

    if (!FUSED) {
        #pragma unroll
        for (int r = 0; r < 4; ++r) {
            const float f = score[r][t];
            const ushort h  = f2bf(f);
            const ushort lo = f2bf(f - bf2f(h));
            a_hi[(size_t)((b << 9) + p0 + r) * 512 + t] = h;
            a_lo[(size_t)((b << 9) + p0 + r) * 512 + t] = lo;
        }
    } else {
        float ax[4] = {};
        #pragma unroll 4
        for (int q = 0; q < 512; ++q) {
            const float h = hq[(size_t)((b << 9) + q) * DDIM + t];
            #pragma unroll
            for (int r = 0; r < 4; ++r) ax[r] = fmaf(score[r][q], h, ax[r]);
        }
        #pragma unroll
        for (int r = 0; r < 4; ++r)
            out[(size_t)((b << 9) + p0 + r) * DDIM + t] = ax[r];
    }
}

// ---------------------------------------------------------------------------
// K3: out = a @ hq (batched). 32x64 tile, grid (8,64) = 512 blocks (2/CU).
// A = a hi/lo bf16 row-major, B = hqT hi/lo.
// ---------------------------------------------------------------------------
__global__ __launch_bounds__(256) void out_mfma(
    const ushort* __restrict__ Ahi, const ushort* __restrict__ Alo,
    const ushort* __restrict__ Bhi_, const ushort* __restrict__ Blo_,
    float* __restrict__ C)
{
    const int m0 = blockIdx.y << 5;       // 32-row tiles, 64 of them
    const int n0 = blockIdx.x << 6;
    const size_t off = (size_t)(m0 >> 9) << 18;
    const ushort* __restrict__ Bhi = Bhi_ + off;
    const ushort* __restrict__ Blo = Blo_ + off;

    __shared__ __attribute__((aligned(16))) ushort As[32 * 128];   // 8KB
    __shared__ __attribute__((aligned(16))) ushort Bs[64 * 128];   // 16KB
    char* AsB = (char*)As;
    char* BsB = (char*)Bs;

    const int t = threadIdx.x;
    const int w = t >> 6, l = t & 63;
    const int moff = (w & 1) << 4, noff = (w >> 1) << 5;

    f32x4 acc[2];
    acc[0] = (f32x4){0.f, 0.f, 0.f, 0.f};
    acc[1] = (f32x4){0.f, 0.f, 0.f, 0.f};

    const int sra = t >> 3, sca = t & 7;          // A: 32 rows x 8 chunks
    const int srb = t >> 2, scb = t & 3;          // B: 64 rows x 4 chunk-pairs
    const size_t argA = (size_t)(m0 + sra) * 512;
    const size_t argB = (size_t)(n0 + srb) * 512;

    for (int k0 = 0; k0 < 512; k0 += 64) {
        const uint4 a0 = *(const uint4*)(Ahi + argA + k0 + (sca << 3));
        const uint4 a1 = *(const uint4*)(Alo + argA + k0 + (sca << 3));
        const uint4 b0 = *(const uint4*)(Bhi + argB + k0 + (scb << 4));
        const uint4 b1 = *(const uint4*)(Bhi + argB + k0 + (scb << 4) + 8);
        const uint4 b2 = *(const uint4*)(Blo + argB + k0 + (scb << 4));
        const uint4 b3 = *(const uint4*)(Blo + argB + k0 + (scb << 4) + 8);
        __syncthreads();
        *(uint4*)(AsB + SWZ(sra, (sca << 4)))          = a0;
        *(uint4*)(AsB + SWZ(sra, 128 + (sca << 4)))    = a1;
        *(uint4*)(BsB + SWZ(srb, (scb << 5)))          = b0;
        *(uint4*)(BsB + SWZ(srb, (scb << 5) + 16))     = b1;
        *(uint4*)(BsB + SWZ(srb, 128 + (scb << 5)))    = b2;
        *(uint4*)(BsB + SWZ(srb, 128 + (scb << 5) + 16)) = b3;
        __syncthreads();
        #pragma unroll
        for (int kc = 0; kc < 2; ++kc) {
            const int colh = (kc << 6) + ((l >> 4) << 4);
            const int ra = moff + (l & 15);
            const short8v ahi = *(const short8v*)(AsB + SWZ(ra, colh));
            const short8v alo = *(const short8v*)(AsB + SWZ(ra, colh + 128));
            #pragma unroll
            for (int nt = 0; nt < 2; ++nt) {
                const int rb = noff + (nt << 4) + (l & 15);
                const short8v bhi = *(const short8v*)(BsB + SWZ(rb, colh));
                const short8v blo = *(const short8v*)(BsB + SWZ(rb, colh + 128));
                acc[nt] = __builtin_amdgcn_mfma_f32_16x16x32_bf16(ahi, bhi, acc[nt], 0, 0, 0);
                acc[nt] = __builtin_amdgcn_mfma_f32_16x16x32_bf16(ahi, blo, acc[nt], 0, 0, 0);
                acc[nt] = __builtin_amdgcn_mfma_f32_16x16x32_bf16(alo, bhi, acc[nt], 0, 0, 0);
            }
        }
    }

    #pragma unroll
    for (int nt = 0; nt < 2; ++nt)
        #pragma unroll
        for (int r = 0; r < 4; ++r) {
            const int row = m0 + moff + ((l >> 4) << 2) + r;
            const int col = n0 + noff + (nt << 4) + (l & 15);
            C[(size_t)row * 512 + col] = acc[nt][r];
        }
}

// ---------------------------------------------------------------------------
// Fallback f32 projection for tiny workspaces.
// ---------------------------------------------------------------------------
__global__ __launch_bounds__(256) void proj_exp_gemm_f32(
    const float* __restrict__ hq, const float* __restrict__ hp,
    const float* __restrict__ W1, const float* __restrict__ W2,
    float* __restrict__ Eq, float* __restrict__ Ep)
{
    const int by = blockIdx.y;
    const float *A, *W;
    if (by < 64) { A = hq; W = W1; }
    else         { A = hp; W = W2; }
    const int m0 = (by & 63) * 32;
    const int n0 = blockIdx.x * 64;

    __shared__ __attribute__((aligned(16))) float As[16][36];
    __shared__ __attribute__((aligned(16))) float Bs[16][68];

    const int tid  = threadIdx.x;
    const int tr = tid >> 4, tc = tid & 15;
    const int la_r = tid >> 3, la_c = (tid & 7) << 1;
    const int lb_r = tid >> 4, lb_c = (tid & 15) << 2;

    float acc[2][4] = {};
    for (int k0 = 0; k0 < 512; k0 += 16) {
        float2 a2 = *(const float2*)(A + (size_t)(m0 + la_r) * 512 + k0 + la_c);
        float4 b4 = *(const float4*)(W + (size_t)(k0 + lb_r) * VDIM + n0 + lb_c);
        __syncthreads();
        As[la_c + 0][la_r] = a2.x;
        As[la_c + 1][la_r] = a2.y;
        *(float4*)&Bs[lb_r][lb_c] = b4;
        __syncthreads();
        #pragma unroll
        for (int kk = 0; kk < 16; ++kk) {
            float2 av = *(const float2*)&As[kk][tr << 1];
            float4 bv = *(const float4*)&Bs[kk][tc << 2];
            const float* ap = (const float*)&av;
            const float* bp = (const float*)&bv;
            #pragma unroll
            for (int i = 0; i < 2; ++i)
                #pragma unroll
                for (int j = 0; j < 4; ++j)
                    acc[i][j] = fmaf(ap[i], bp[j], acc[i][j]);
        }
    }
    if (by < 64) {
        float4* EqT = (float4*)Eq;
        const int bb = m0 >> 9, qb = m0 & 511;
        const int vi = (blockIdx.x << 4) + tc;
        #pragma unroll
        for (int i = 0; i < 2; ++i) {
            float4 r;
            r.x = __builtin_amdgcn_exp2f(acc[i][0] * TWO_LOG2E);
            r.y = __builtin_amdgcn_exp2f(acc[i][1] * TWO_LOG2E);
            r.z = __builtin_amdgcn_exp2f(acc[i][2] * TWO_LOG2E);
            r.w = __builtin_amdgcn_exp2f(acc[i][3] * TWO_LOG2E);
            EqT[((size_t)(bb << 6) + vi) * 512 + qb + (tr << 1) + i] = r;
        }
    } else {
        #pragma unroll
        for (int i = 0; i < 2; ++i) {
            float4 r;
            r.x = __builtin_amdgcn_exp2f(acc[i][0] * TWO_LOG2E);
            r.y = __builtin_amdgcn_exp2f(acc[i][1] * TWO_LOG2E);
            r.z = __builtin_amdgcn_exp2f(acc[i][2] * TWO_LOG2E);
            r.w = __builtin_amdgcn_exp2f(acc[i][3] * TWO_LOG2E);
            *(float4*)(Ep + (size_t)(m0 + (tr << 1) + i) * VDIM + n0 + (tc << 2)) = r;
        }
    }
}

// ---------------------------------------------------------------------------
extern "C" void kernel_launch(void* const* d_in, const int* in_sizes, int n_in,
                              void* d_out, int out_size, void* d_ws, size_t ws_size,
                              hipStream_t stream)
{
    const float* hq = (const float*)d_in[0];   // [4,512,512]
    const float* hp = (const float*)d_in[1];   // [4,512,512]
    const float* W1 = (const float*)d_in[2];   // [512,256]
    const float* W2 = (const float*)d_in[3];   // [512,256]
    const float* vv = (const float*)d_in[4];   // [256]
    float* out = (float*)d_out;                // [4,512,512]

    float* EqT = (float*)d_ws;                 // [4][64][512] float4 = 2MB
    float* Ep  = EqT + 524288;                 // [2048,256] f32 = 2MB
    ushort* u  = (ushort*)(Ep + 524288);
    ushort* hqT_hi = u; u += 1048576;
    ushort* hqT_lo = u; u += 1048576;
    ushort* W1T_hi = u; u += 131072;
    ushort* W1T_lo = u; u += 131072;
    ushort* W2T_hi = u; u += 131072;
    ushort* W2T_lo = u; u += 131072;
    ushort* a_hi   = u; u += 1048576;
    ushort* a_lo   = u; u += 1048576;
    const size_t need = (size_t)((char*)u - (char*)d_ws);

    if (ws_size >= need) {
        w_transpose<<<dim3(4, 8, 2), 256, 0, stream>>>(
            W1, W2, W1T_hi, W1T_lo, W2T_hi, W2T_lo);
        proj_and_transpose<<<512, 256, 0, stream>>>(
            hq, hp, W1T_hi, W1T_lo, W2T_hi, W2T_lo, hqT_hi, hqT_lo, EqT, Ep);
        score_softmax<false><<<512, 512, 0, stream>>>(
            (const float4*)EqT, Ep, vv, hq, a_hi, a_lo, out);
        out_mfma<<<dim3(8, 64), 256, 0, stream>>>(a_hi, a_lo, hqT_hi, hqT_lo, out);
    } else {
        proj_exp_gemm_f32<<<dim3(4, 128), 256, 0, stream>>>(hq, hp, W1, W2, EqT, Ep);
        score_softmax<true><<<512, 512, 0, stream>>>(
            (const float4*)EqT, Ep, vv, hq, nullptr, nullptr, out);
    }
}